// Round 3
// baseline (223.026 us; speedup 1.0000x reference)
//
#include <hip/hip_runtime.h>
#include <hip/hip_bf16.h>
#include <math.h>

// Problem constants (fixed by setup_inputs)
#define BATCH 512
#define NADV  16
#define NROWS (BATCH*NADV)     // 8192
#define DS    32
#define DO    32
#define DIM   64               // DS + DO
#define HID   128
#define WCOLS (DIM*HID)        // 8192 columns of hw2
#define LSTR  136              // padded f16 LDS row stride (2-way bank aliasing)
#define PACK_BLOCKS 276
#define NBLK  512              // 2 blocks/CU x 256 CU — all co-resident

typedef _Float16 half8 __attribute__((ext_vector_type(8)));
typedef float floatx4 __attribute__((ext_vector_type(4)));

__device__ inline void async_ld16(void* lds, const void* g) {
    __builtin_amdgcn_global_load_lds(
        (const __attribute__((address_space(1))) void*)g,
        (__attribute__((address_space(3))) void*)lds, 16, 0, 0);
}

// Hand-rolled grid barrier: device-scope atomics + agent fences (cross-XCD
// L2 writeback/invalidate). Counter is pre-zeroed by hipMemsetAsync in
// kernel_launch. Safe: grid=512 = exact co-residency capacity
// (LDS 70656 B -> 2 blk/CU; __launch_bounds__(256,2) -> VGPR<=256).
__device__ inline void grid_barrier(unsigned* cnt) {
    __syncthreads();
    if (threadIdx.x == 0) {
        __threadfence();                 // release: make my writes visible
        atomicAdd(cnt, 1u);
        while (__hip_atomic_load(cnt, __ATOMIC_RELAXED,
                                 __HIP_MEMORY_SCOPE_AGENT) < NBLK)
            __builtin_amdgcn_s_sleep(2);
        __threadfence();                 // acquire: invalidate stale caches
    }
    __syncthreads();
}

// ---------------------------------------------------------------------------
// ONE kernel, 512 blocks x 256 threads, 3 phases + hand-rolled grid barriers.
// LDS: 70656 B union (max phase 2) -> 2 blocks/CU -> all 512 co-resident.
//
// Phase 1: pack units [0,276): weights -> MFMA-native f16 chunks
//     chunk(ct,kt)[lane*8+e] = W[kt*32+(lane>>4)*8+e][ct*16+(lane&15)]
//   h units (all 512 blocks; pack blocks take a second unit):
//     h = relu(x@hw1+hb1) via MFMA (A from obs/latent f32->f16 in regs,
//     B gathered from L1-hot hw1).
// Phase 2: hyper GEMM. block = 128 rows x 16 emb-cols x all 64 d; 4 waves,
//   each wave owns 32 rows (2x16) -> R=2 B-reuse per ds_read_b128.
//   x staged transposed (xs_t[d][row]) -> 1 b128 broadcast per reg-tile.
//   jt = b&7 XCD-aligns each col-tile's 256 KB B-set with one L2.
// Phase 3: fused tail per batch group (vw/aw MLPs, softmax, weighted sum),
//   4 waves x 2 col-tiles each.
// ---------------------------------------------------------------------------
__global__ __launch_bounds__(256, 2)
void k_fused(const float* __restrict__ obs, const float* __restrict__ latent,
             const float* __restrict__ hw1, const float* __restrict__ hb1,
             const float* __restrict__ hw2, const float* __restrict__ hb2,
             const float* __restrict__ vw1, const float* __restrict__ vb1,
             const float* __restrict__ vw2, const float* __restrict__ vb2,
             const float* __restrict__ aw1, const float* __restrict__ ab1,
             const float* __restrict__ aw2, const float* __restrict__ ab2,
             const float* __restrict__ aw3, const float* __restrict__ ab3,
             float* __restrict__ out,
             _Float16* __restrict__ hf, _Float16* __restrict__ w2p,
             _Float16* __restrict__ embf, _Float16* __restrict__ emeanf,
             _Float16* __restrict__ vw1p, _Float16* __restrict__ vw2p,
             _Float16* __restrict__ aw1p, _Float16* __restrict__ aw2p,
             unsigned* __restrict__ bar) {
    __shared__ __align__(16) char smraw[70656];
    int b   = blockIdx.x;
    int tid = threadIdx.x;
    int wave = tid >> 6, lane = tid & 63, l15 = lane & 15, quad = lane >> 4;

    // ===================== PHASE 1: pack + h =====================
    {
        float* smem = (float*)smraw;   // [32*132] = 16.9 KB
        if (b < PACK_BLOCKS) {
            const float* src; _Float16* dst; int N, Kt, jb, kt;
            if (b < 256)      { src = hw2; dst = w2p;  N = WCOLS; Kt = 4; jb = b >> 2; kt = b & 3; }
            else if (b < 260) { src = vw1; dst = vw1p; N = HID;   Kt = 4; jb = 0; kt = b - 256; }
            else if (b < 264) { src = vw2; dst = vw2p; N = HID;   Kt = 4; jb = 0; kt = b - 260; }
            else if (b < 272) { src = aw1; dst = aw1p; N = HID;   Kt = 8; jb = 0; kt = b - 264; }
            else              { src = aw2; dst = aw2p; N = HID;   Kt = 4; jb = 0; kt = b - 272; }
            // coalesced read: 32 k-rows x 128 j-cols (512 B contiguous per row)
            for (int i = tid; i < 32 * 32; i += 256) {
                int r = i >> 5, c4 = (i & 31) * 4;
                *(float4*)&smem[r * 132 + c4] =
                    *(const float4*)(src + (size_t)(kt * 32 + r) * N + jb * 128 + c4);
            }
            __syncthreads();
            // write 8 chunks (ctl 0..7), each 1 KB, fully contiguous stores
            for (int i = tid; i < 8 * 64; i += 256) {
                int ctl = i >> 6, ln = i & 63;
                int ct = jb * 8 + ctl;
                int rbase = (ln >> 4) * 8, cc = ctl * 16 + (ln & 15);
                half8 v;
#pragma unroll
                for (int e = 0; e < 8; ++e) v[e] = (_Float16)smem[(rbase + e) * 132 + cc];
                *(half8*)(dst + ((size_t)ct * Kt + kt) * 512 + ln * 8) = v;
            }
        }
        // h unit: pack blocks take group b+236; others group b-276.
        int hgroup = (b < PACK_BLOCKS) ? (b + NBLK - PACK_BLOCKS) : (b - PACK_BLOCKS);
        {
            int n0 = hgroup * 16;
            // A-frag: af2[ks][e] = x[n0+l15][ks*32 + quad*8 + e]  (f32 -> f16)
            half8 af2[2];
            {
                int n = n0 + l15;
                const float* orow = obs + (size_t)(n & (BATCH - 1)) * DS + quad * 8;
                const float* lrow = latent + (size_t)n * DO + quad * 8;
                float4 a0 = *(const float4*)orow;
                float4 a1 = *(const float4*)(orow + 4);
                float4 c0 = *(const float4*)lrow;
                float4 c1 = *(const float4*)(lrow + 4);
                float a8[8] = {a0.x, a0.y, a0.z, a0.w, a1.x, a1.y, a1.z, a1.w};
                float c8[8] = {c0.x, c0.y, c0.z, c0.w, c1.x, c1.y, c1.z, c1.w};
#pragma unroll
                for (int e = 0; e < 8; ++e) {
                    af2[0][e] = (_Float16)a8[e];
                    af2[1][e] = (_Float16)c8[e];
                }
            }
#pragma unroll
            for (int cti = 0; cti < 2; ++cti) {
                int ct = wave * 2 + cti;
                float bb = hb1[ct * 16 + l15];
                floatx4 acc = {bb, bb, bb, bb};
#pragma unroll
                for (int ks = 0; ks < 2; ++ks) {
                    // B-frag gather: hw1[(ks*32+quad*8+e)][ct*16+l15] (L1-hot)
                    const float* wsrc = hw1 + (size_t)(ks * 32 + quad * 8) * HID + ct * 16 + l15;
                    half8 bf;
#pragma unroll
                    for (int e = 0; e < 8; ++e) bf[e] = (_Float16)wsrc[e * HID];
                    acc = __builtin_amdgcn_mfma_f32_16x16x32_f16(af2[ks], bf, acc, 0, 0, 0);
                }
#pragma unroll
                for (int reg = 0; reg < 4; ++reg)
                    hf[(size_t)(n0 + quad * 4 + reg) * HID + ct * 16 + l15] =
                        (_Float16)fmaxf(acc[reg], 0.f);
            }
        }
    }
    grid_barrier(bar + 0);

    // ===================== PHASE 2: hyper GEMM =====================
    {
        _Float16 (*Bs)[4][512] = (_Float16(*)[4][512])smraw;          // 32 KB
        float (*xs_t)[132]     = (float(*)[132])(smraw + 32768);      // 33.8 KB
        float* bias_s          = (float*)(smraw + 66560);             // 4 KB
        int jt = b & 7;          // emb col-tile (16 cols) — XCD-aligned B reuse
        int rt = b >> 3;         // row-tile: rows [rt*128, +128)
        int n0 = rt * 128;
        int j0 = jt * 16;

        // stage x TRANSPOSED (obs[n%512] ++ latent[n]) and bias slice
        for (int i = tid; i < 128 * 16; i += 256) {
            int r = i >> 4, c4 = (i & 15) * 4;
            float4 v;
            if (c4 < DS) v = *(const float4*)(obs + ((n0 + r) & (BATCH - 1)) * DS + c4);
            else         v = *(const float4*)(latent + (size_t)(n0 + r) * DO + (c4 - DS));
            xs_t[c4 + 0][r] = v.x;
            xs_t[c4 + 1][r] = v.y;
            xs_t[c4 + 2][r] = v.z;
            xs_t[c4 + 3][r] = v.w;
        }
        for (int i = tid; i < 64 * 16; i += 256)
            bias_s[i] = hb2[(i >> 4) * HID + j0 + (i & 15)];

        // A fragments: wave owns rows [n0 + wave*32, +32)
        half8 af[2][4];
#pragma unroll
        for (int t = 0; t < 2; ++t) {
            const _Float16* arow = hf + (size_t)(n0 + wave * 32 + t * 16 + l15) * HID;
#pragma unroll
            for (int ks = 0; ks < 4; ++ks)
                af[t][ks] = *(const half8*)(arow + ks * 32 + quad * 8);
        }

        float emb_acc[2][4] = {{0.f, 0.f, 0.f, 0.f}, {0.f, 0.f, 0.f, 0.f}};

        for (int d8 = 0; d8 < 8; ++d8) {
            // stage B: wave stages d-tiles {2w, 2w+1} as 4 x 1 KB bursts each
#pragma unroll
            for (int s = 0; s < 2; ++s) {
                int dt = wave * 2 + s;
                int ct = (d8 * 8 + dt) * 8 + jt;
                const _Float16* src = w2p + (size_t)ct * 2048 + lane * 8;
                _Float16* dst = &Bs[dt][0][0];
#pragma unroll
                for (int kt = 0; kt < 4; ++kt)
                    async_ld16(dst + kt * 512, src + kt * 512);
            }
            __syncthreads();   // staging done (also covers xs_t/bias on iter 0)

#pragma unroll
            for (int dd = 0; dd < 8; ++dd) {
                int d = d8 * 8 + dd;
                float bb = bias_s[d * 16 + l15];
                floatx4 acc0 = {bb, bb, bb, bb};
                floatx4 acc1 = {bb, bb, bb, bb};
#pragma unroll
                for (int ks = 0; ks < 4; ++ks) {
                    half8 bfr = *(const half8*)&Bs[dd][ks][lane * 8];
                    acc0 = __builtin_amdgcn_mfma_f32_16x16x32_f16(af[0][ks], bfr, acc0, 0, 0, 0);
                    acc1 = __builtin_amdgcn_mfma_f32_16x16x32_f16(af[1][ks], bfr, acc1, 0, 0, 0);
                }
                floatx4 xv0 = *(const floatx4*)&xs_t[d][wave * 32 + quad * 4];
                floatx4 xv1 = *(const floatx4*)&xs_t[d][wave * 32 + 16 + quad * 4];
#pragma unroll
                for (int reg = 0; reg < 4; ++reg) {
                    emb_acc[0][reg] = fmaf(xv0[reg], fmaxf(acc0[reg], 0.f), emb_acc[0][reg]);
                    emb_acc[1][reg] = fmaf(xv1[reg], fmaxf(acc1[reg], 0.f), emb_acc[1][reg]);
                }
            }
            __syncthreads();   // done consuming Bs; safe to restage
        }

        // epilogue: tanh -> embf; each 16-row tile = one batch -> mean direct
#pragma unroll
        for (int t = 0; t < 2; ++t) {
            float e[4];
#pragma unroll
            for (int reg = 0; reg < 4; ++reg) {
                e[reg] = tanhf(emb_acc[t][reg]);
                embf[(size_t)(n0 + wave * 32 + t * 16 + quad * 4 + reg) * HID + j0 + l15] =
                    (_Float16)e[reg];
            }
            float s = e[0] + e[1] + e[2] + e[3];
            s += __shfl_xor(s, 16, 64);
            s += __shfl_xor(s, 32, 64);
            if (quad == 0)
                emeanf[(size_t)(rt * 8 + wave * 2 + t) * HID + j0 + l15] =
                    (_Float16)(s * (1.f / 16));
        }
    }
    grid_barrier(bar + 64);

    // ===================== PHASE 3: fused tail =====================
    {
        _Float16 (*embs)[LSTR]  = (_Float16(*)[LSTR])smraw;
        _Float16 (*means)[LSTR] = (_Float16(*)[LSTR])(smraw + 4352);
        _Float16 (*tAs)[LSTR]   = (_Float16(*)[LSTR])(smraw + 8704);
        _Float16 (*tBs)[LSTR]   = (_Float16(*)[LSTR])(smraw + 13056);
        float (*scr)[16]        = (float(*)[16])(smraw + 17408);
        float* satt             = (float*)(smraw + 18432);
        float* att              = (float*)(smraw + 18496);
        int g = b;                // batch group 0..511
        int n0 = g * 16;

        // stage emb rows + mean rows (512 half8 loads = 2/thread)
        for (int i = tid; i < 512; i += 256) {
            int m = i >> 8, r = (i >> 4) & 15, c8 = (i & 15) * 8;
            if (m == 0)
                *(half8*)&embs[r][c8] = *(const half8*)(embf + (size_t)(n0 + r) * HID + c8);
            else
                // mean_rep[n] = emb_mean[n % 512] (torch .repeat tiling) — exact.
                *(half8*)&means[r][c8] =
                    *(const half8*)(emeanf + (size_t)((n0 + r) & 511) * HID + c8);
        }
        __syncthreads();

        half8 av[4], amean[4];
#pragma unroll
        for (int ks = 0; ks < 4; ++ks) {
            av[ks]    = *(const half8*)&embs[l15][ks * 32 + quad * 8];
            amean[ks] = *(const half8*)&means[l15][ks * 32 + quad * 8];
        }

        // ---- v1: t1 = relu(emb @ vw1 + vb1) ----  (wave handles ct = wave, wave+4)
#pragma unroll
        for (int cti = 0; cti < 2; ++cti) {
            int ct = wave + cti * 4;
            float bb = vb1[ct * 16 + l15];
            floatx4 acc = {bb, bb, bb, bb};
#pragma unroll
            for (int ks = 0; ks < 4; ++ks) {
                half8 bfr = *(const half8*)(vw1p + ((size_t)ct * 4 + ks) * 512 + lane * 8);
                acc = __builtin_amdgcn_mfma_f32_16x16x32_f16(av[ks], bfr, acc, 0, 0, 0);
            }
#pragma unroll
            for (int reg = 0; reg < 4; ++reg)
                tAs[quad * 4 + reg][ct * 16 + l15] = (_Float16)fmaxf(acc[reg], 0.f);
        }
        __syncthreads();

        half8 at4[4];
#pragma unroll
        for (int ks = 0; ks < 4; ++ks)
            at4[ks] = *(const half8*)&tAs[l15][ks * 32 + quad * 8];

        // ---- v2: vals = relu(t1 @ vw2 + vb2), kept in registers ----
        floatx4 vacc[2];
#pragma unroll
        for (int cti = 0; cti < 2; ++cti) {
            int ct = wave + cti * 4;
            float bb = vb2[ct * 16 + l15];
            vacc[cti] = (floatx4){bb, bb, bb, bb};
#pragma unroll
            for (int ks = 0; ks < 4; ++ks) {
                half8 bfr = *(const half8*)(vw2p + ((size_t)ct * 4 + ks) * 512 + lane * 8);
                vacc[cti] = __builtin_amdgcn_mfma_f32_16x16x32_f16(at4[ks], bfr, vacc[cti], 0, 0, 0);
            }
        }

        // ---- a1: ta1 = relu([emb|mean] @ aw1 + ab1), K=256 ----
#pragma unroll
        for (int cti = 0; cti < 2; ++cti) {
            int ct = wave + cti * 4;
            float bb = ab1[ct * 16 + l15];
            floatx4 aacc = {bb, bb, bb, bb};
#pragma unroll
            for (int ks = 0; ks < 8; ++ks) {
                half8 bfr = *(const half8*)(aw1p + ((size_t)ct * 8 + ks) * 512 + lane * 8);
                half8 a = (ks < 4) ? av[ks] : amean[ks - 4];
                aacc = __builtin_amdgcn_mfma_f32_16x16x32_f16(a, bfr, aacc, 0, 0, 0);
            }
#pragma unroll
            for (int reg = 0; reg < 4; ++reg)
                tBs[quad * 4 + reg][ct * 16 + l15] = (_Float16)fmaxf(aacc[reg], 0.f);
        }
        __syncthreads();

        half8 aa[4];
#pragma unroll
        for (int ks = 0; ks < 4; ++ks)
            aa[ks] = *(const half8*)&tBs[l15][ks * 32 + quad * 8];

        // ---- a2: t2 = relu(ta1 @ aw2 + ab2) ----
        floatx4 a2acc[2];
#pragma unroll
        for (int cti = 0; cti < 2; ++cti) {
            int ct = wave + cti * 4;
            float bb = ab2[ct * 16 + l15];
            a2acc[cti] = (floatx4){bb, bb, bb, bb};
#pragma unroll
            for (int ks = 0; ks < 4; ++ks) {
                half8 bfr = *(const half8*)(aw2p + ((size_t)ct * 4 + ks) * 512 + lane * 8);
                a2acc[cti] = __builtin_amdgcn_mfma_f32_16x16x32_f16(aa[ks], bfr, a2acc[cti], 0, 0, 0);
            }
        }
        __syncthreads();   // everyone done reading tAs (at4)
#pragma unroll
        for (int cti = 0; cti < 2; ++cti) {
            int ct = wave + cti * 4;
#pragma unroll
            for (int reg = 0; reg < 4; ++reg)
                tAs[quad * 4 + reg][ct * 16 + l15] = (_Float16)fmaxf(a2acc[cti][reg], 0.f);
        }
        __syncthreads();

        // ---- scores: s[r] = t2[r,:] . aw3 + ab3 ----
        {
            int r = tid >> 4, ch = tid & 15;
            float p = 0.f;
#pragma unroll
            for (int k = 0; k < 8; ++k)
                p += (float)tAs[r][ch * 8 + k] * aw3[ch * 8 + k];
            scr[r][ch] = p;
        }
        __syncthreads();
        if (tid < 16) {
            float s = ab3[0];
#pragma unroll
            for (int ch = 0; ch < 16; ++ch) s += scr[tid][ch];
            satt[tid] = s;
        }
        __syncthreads();
        if (tid < 16) {
            float m = -1e30f;
#pragma unroll
            for (int a = 0; a < 16; ++a) m = fmaxf(m, satt[a]);
            float S = 0.f;
#pragma unroll
            for (int a = 0; a < 16; ++a) S += expf(satt[a] - m);
            att[tid] = expf(satt[tid] - m) / S;
        }
        __syncthreads();

        // ---- weighted sum: out[g, col] = sum_a att[a] * vals[a, col] ----
#pragma unroll
        for (int cti = 0; cti < 2; ++cti) {
            int ct = wave + cti * 4;
            float p = 0.f;
#pragma unroll
            for (int reg = 0; reg < 4; ++reg)
                p += att[quad * 4 + reg] * fmaxf(vacc[cti][reg], 0.f);
            p += __shfl_xor(p, 16, 64);
            p += __shfl_xor(p, 32, 64);
            if (quad == 0) out[(size_t)g * HID + ct * 16 + l15] = p;
        }
    }
}

// ---------------------------------------------------------------------------
extern "C" void kernel_launch(void* const* d_in, const int* in_sizes, int n_in,
                              void* d_out, int out_size, void* d_ws, size_t ws_size,
                              hipStream_t stream) {
    const float* obs = (const float*)d_in[0];
    const float* lat = (const float*)d_in[1];
    const float* hw1 = (const float*)d_in[2];
    const float* hb1 = (const float*)d_in[3];
    const float* hw2 = (const float*)d_in[4];
    const float* hb2 = (const float*)d_in[5];
    const float* vw1 = (const float*)d_in[6];
    const float* vb1 = (const float*)d_in[7];
    const float* vw2 = (const float*)d_in[8];
    const float* vb2 = (const float*)d_in[9];
    const float* aw1 = (const float*)d_in[10];
    const float* ab1 = (const float*)d_in[11];
    const float* aw2 = (const float*)d_in[12];
    const float* ab2 = (const float*)d_in[13];
    const float* aw3 = (const float*)d_in[14];
    const float* ab3 = (const float*)d_in[15];
    float* out = (float*)d_out;

    char* ws = (char*)d_ws;
    _Float16*  hf     = (_Float16*)ws;  ws += (size_t)NROWS * HID * 2;     // 2 MB
    _Float16*  w2p    = (_Float16*)ws;  ws += (size_t)WCOLS * HID * 2;     // 2 MB
    _Float16*  embf   = (_Float16*)ws;  ws += (size_t)NROWS * HID * 2;     // 2 MB
    _Float16*  emeanf = (_Float16*)ws;  ws += (size_t)BATCH * HID * 2;     // 128 KB
    _Float16*  vw1p   = (_Float16*)ws;  ws += (size_t)HID * HID * 2;       // 32 KB
    _Float16*  vw2p   = (_Float16*)ws;  ws += (size_t)HID * HID * 2;
    _Float16*  aw1p   = (_Float16*)ws;  ws += (size_t)2 * HID * HID * 2;   // 64 KB
    _Float16*  aw2p   = (_Float16*)ws;  ws += (size_t)HID * HID * 2;
    // barrier counters: fixed offset past all buffers, 2 cachelines
    unsigned* bar = (unsigned*)((char*)d_ws + (8u << 20));
    hipMemsetAsync(bar, 0, 512, stream);

    hipLaunchKernelGGL(k_fused, dim3(NBLK), dim3(256), 0, stream,
                       obs, lat, hw1, hb1, hw2, hb2, vw1, vb1, vw2, vb2,
                       aw1, ab1, aw2, ab2, aw3, ab3, out,
                       hf, w2p, embf, emeanf, vw1p, vw2p, aw1p, aw2p, bar);
}

// Round 4
// 138.116 us; speedup vs baseline: 1.6148x; 1.6148x over previous
//
#include <hip/hip_runtime.h>
#include <hip/hip_bf16.h>
#include <math.h>

// Problem constants (fixed by setup_inputs)
#define BATCH 512
#define NADV  16
#define NROWS (BATCH*NADV)     // 8192
#define DS    32
#define DO    32
#define DIM   64               // DS + DO
#define HID   128
#define WCOLS (DIM*HID)        // 8192 columns of hw2
#define LSTR  136              // padded f16 LDS row stride (2-way bank aliasing)

typedef _Float16 half8 __attribute__((ext_vector_type(8)));
typedef float floatx4 __attribute__((ext_vector_type(4)));

// ---------------------------------------------------------------------------
// Kernel MAIN: grid 532 x 256 threads.
//  Blocks [0,512): hyper GEMM, block = 128 rows x 16 emb-cols x all 64 d.
//    Self-contained (no prep kernel, no hf/w2p workspace):
//    - h = relu(x@hw1+hb1) computed IN-BLOCK via MFMA (hw1 B-frags gathered
//      from L2-hot f32; D written to wave-private LDS scratch, read back as
//      A-frags). Only this block's 128 rows are needed -> block-local dep.
//    - B-tiles gathered from hw2 f32 directly (4 cache lines / instr;
//      same-jt blocks land on the same XCD (b&7) and share the 512 KB slice
//      in that XCD's L2), converted to f16 in regs, ds_written in MFMA-
//      native layout. Double-buffered 2-dtile chunks, issue-early /
//      write-late, ONE barrier per iter (min-2-phase pipeline).
//    - 4 waves, each owns 32 rows (2x16 tiles) -> R=2 B-reuse per ds_read.
//    - epilogue: emb = tanh(acc) -> embf f16; 16-row tile = one batch ->
//      emeanf direct.
//  Blocks [512,532): pack small tail weights (vw1,vw2,aw1,aw2) into
//    MFMA-native f16 chunks for k_tail:
//    chunk(ct,kt)[lane*8+e] = W[kt*32+(lane>>4)*8+e][ct*16+(lane&15)]
// ---------------------------------------------------------------------------
__global__ __launch_bounds__(256, 2)
void k_main(const float* __restrict__ obs, const float* __restrict__ latent,
            const float* __restrict__ hw1, const float* __restrict__ hb1,
            const float* __restrict__ hw2, const float* __restrict__ hb2,
            const float* __restrict__ vw1, const float* __restrict__ vw2,
            const float* __restrict__ aw1, const float* __restrict__ aw2,
            _Float16* __restrict__ embf, _Float16* __restrict__ emeanf,
            _Float16* __restrict__ vw1p, _Float16* __restrict__ vw2p,
            _Float16* __restrict__ aw1p, _Float16* __restrict__ aw2p) {
    // LDS map (71680 B total -> 2 blocks/CU):
    //   [0,33792)      xs_t[64][132] f32   (transposed x, persists)
    //   [33792,67584)  hscr[4][32][132] f16 (h scratch, pre-loop)
    //                  Bs[2][2][4][512] f16 (16 KB, loop; overlaps hscr)
    //   [67584,71680)  bias_s[64*16] f32   (persists)
    __shared__ __align__(16) char smraw[71680];
    int b   = blockIdx.x;
    int tid = threadIdx.x;
    int wave = tid >> 6, lane = tid & 63, l15 = lane & 15, quad = lane >> 4;

    if (b >= 512) {
        // -------- small-weight pack (20 units) --------
        float* smem = (float*)smraw;   // 32 x 132 f32
        int u = b - 512;
        const float* src; _Float16* dst; int Kt, kt;
        if (u < 4)       { src = vw1; dst = vw1p; Kt = 4; kt = u; }
        else if (u < 8)  { src = vw2; dst = vw2p; Kt = 4; kt = u - 4; }
        else if (u < 16) { src = aw1; dst = aw1p; Kt = 8; kt = u - 8; }
        else             { src = aw2; dst = aw2p; Kt = 4; kt = u - 16; }
        for (int i = tid; i < 32 * 32; i += 256) {
            int r = i >> 5, c4 = (i & 31) * 4;
            *(float4*)&smem[r * 132 + c4] =
                *(const float4*)(src + (size_t)(kt * 32 + r) * HID + c4);
        }
        __syncthreads();
        for (int i = tid; i < 8 * 64; i += 256) {
            int ctl = i >> 6, ln = i & 63;
            int rbase = (ln >> 4) * 8, cc = ctl * 16 + (ln & 15);
            half8 v;
#pragma unroll
            for (int e = 0; e < 8; ++e) v[e] = (_Float16)smem[(rbase + e) * 132 + cc];
            *(half8*)(dst + ((size_t)ctl * Kt + kt) * 512 + ln * 8) = v;
        }
        return;
    }

    // -------- hyper GEMM block --------
    float (*xs_t)[132] = (float(*)[132])smraw;
    _Float16* hscr_all = (_Float16*)(smraw + 33792);
    _Float16 (*Bs)[2][4][512] = (_Float16(*)[2][4][512])(smraw + 33792);
    float* bias_s = (float*)(smraw + 67584);

    int jt = b & 7;          // emb col-tile (16 cols) — XCD-aligned B reuse
    int rt = b >> 3;         // row-tile: rows [rt*128, +128)
    int n0 = rt * 128;
    int j0 = jt * 16;

    // stage x TRANSPOSED (obs[n%512] ++ latent[n]) and bias slice
    for (int i = tid; i < 128 * 16; i += 256) {
        int r = i >> 4, c4 = (i & 15) * 4;
        float4 v;
        if (c4 < DS) v = *(const float4*)(obs + ((n0 + r) & (BATCH - 1)) * DS + c4);
        else         v = *(const float4*)(latent + (size_t)(n0 + r) * DO + (c4 - DS));
        xs_t[c4 + 0][r] = v.x;
        xs_t[c4 + 1][r] = v.y;
        xs_t[c4 + 2][r] = v.z;
        xs_t[c4 + 3][r] = v.w;
    }
    for (int i = tid; i < 64 * 16; i += 256)
        bias_s[i] = hb2[(i >> 4) * HID + j0 + (i & 15)];

    // ---- in-block h = relu(x @ hw1 + hb1) for this block's 128 rows ----
    // wave handles its own 32 rows (2 tiles of 16); wave-private scratch.
    _Float16* hscr = hscr_all + wave * (32 * 132);
    half8 af[2][4];          // big-GEMM A-frags (filled below)
    {
        // A-frags of the h-GEMM: x[n][ks*32+quad*8+e], f32 -> f16
        half8 afx[2][2];
#pragma unroll
        for (int t = 0; t < 2; ++t) {
            int n = n0 + wave * 32 + t * 16 + l15;
            const float* orow = obs + (size_t)(n & (BATCH - 1)) * DS + quad * 8;
            const float* lrow = latent + (size_t)n * DO + quad * 8;
#pragma unroll
            for (int e = 0; e < 4; ++e) {
                afx[t][0][e]     = (_Float16)orow[e];
                afx[t][0][e + 4] = (_Float16)orow[e + 4];
                afx[t][1][e]     = (_Float16)lrow[e];
                afx[t][1][e + 4] = (_Float16)lrow[e + 4];
            }
        }
#pragma unroll
        for (int ct = 0; ct < 8; ++ct) {
            half8 bf[2];
#pragma unroll
            for (int ks = 0; ks < 2; ++ks) {
                const float* wsrc = hw1 + (size_t)(ks * 32 + quad * 8) * HID + ct * 16 + l15;
#pragma unroll
                for (int e = 0; e < 8; ++e) bf[ks][e] = (_Float16)wsrc[(size_t)e * HID];
            }
            float bb = hb1[ct * 16 + l15];
#pragma unroll
            for (int t = 0; t < 2; ++t) {
                floatx4 acc = {bb, bb, bb, bb};
#pragma unroll
                for (int ks = 0; ks < 2; ++ks)
                    acc = __builtin_amdgcn_mfma_f32_16x16x32_f16(afx[t][ks], bf[ks], acc, 0, 0, 0);
                // D: row = t*16 + quad*4 + reg, col = ct*16 + l15
#pragma unroll
                for (int reg = 0; reg < 4; ++reg)
                    hscr[(t * 16 + quad * 4 + reg) * 132 + ct * 16 + l15] =
                        (_Float16)fmaxf(acc[reg], 0.f);
            }
        }
        // read back as big-GEMM A-frags (wave-private, same-wave ordering)
#pragma unroll
        for (int t = 0; t < 2; ++t)
#pragma unroll
            for (int ks = 0; ks < 4; ++ks)
                af[t][ks] = *(const half8*)&hscr[(t * 16 + l15) * 132 + ks * 32 + quad * 8];
    }
    __syncthreads();   // hscr reads done everywhere; xs_t/bias staged

    // ---- main loop: 32 iters x 2 dtiles, dbuf Bs, 1 barrier/iter ----
    // Bs[buf][dt][kt][lane*8+e] = (f16) hw2[kt*32+quad*8+e][d*128+j0+l15]
    // wave stages chunks {2*wave, 2*wave+1}, chunk c: dt=c>>2, kt=c&3.
    float emb_acc[2][4] = {{0.f, 0.f, 0.f, 0.f}, {0.f, 0.f, 0.f, 0.f}};

    {   // prologue: stage it=0 into buf 0
        float g[16];
#pragma unroll
        for (int ci = 0; ci < 2; ++ci) {
            int c = wave * 2 + ci, dt = c >> 2, kt = c & 3;
            const float* src = hw2 + (size_t)(kt * 32 + quad * 8) * WCOLS
                                   + (size_t)dt * 128 + j0 + l15;
#pragma unroll
            for (int e = 0; e < 8; ++e) g[ci * 8 + e] = src[(size_t)e * WCOLS];
        }
#pragma unroll
        for (int ci = 0; ci < 2; ++ci) {
            int c = wave * 2 + ci, dt = c >> 2, kt = c & 3;
            half8 v;
#pragma unroll
            for (int e = 0; e < 8; ++e) v[e] = (_Float16)g[ci * 8 + e];
            *(half8*)&Bs[0][dt][kt][lane * 8] = v;
        }
    }
    __syncthreads();

    for (int it = 0; it < 32; ++it) {
        int cb = it & 1;
        bool have = (it < 31);
        float g[16];
        if (have) {   // issue next-iter gathers EARLY (latency hides under MFMA)
#pragma unroll
            for (int ci = 0; ci < 2; ++ci) {
                int c = wave * 2 + ci, dt = c >> 2, kt = c & 3;
                int d = (it + 1) * 2 + dt;
                const float* src = hw2 + (size_t)(kt * 32 + quad * 8) * WCOLS
                                       + (size_t)d * 128 + j0 + l15;
#pragma unroll
                for (int e = 0; e < 8; ++e) g[ci * 8 + e] = src[(size_t)e * WCOLS];
            }
        }
        // compute current buffer (2 dtiles)
#pragma unroll
        for (int dd = 0; dd < 2; ++dd) {
            int d = it * 2 + dd;
            float bb = bias_s[d * 16 + l15];
            floatx4 acc0 = {bb, bb, bb, bb};
            floatx4 acc1 = {bb, bb, bb, bb};
#pragma unroll
            for (int ks = 0; ks < 4; ++ks) {
                half8 bfr = *(const half8*)&Bs[cb][dd][ks][lane * 8];
                acc0 = __builtin_amdgcn_mfma_f32_16x16x32_f16(af[0][ks], bfr, acc0, 0, 0, 0);
                acc1 = __builtin_amdgcn_mfma_f32_16x16x32_f16(af[1][ks], bfr, acc1, 0, 0, 0);
            }
            floatx4 xv0 = *(const floatx4*)&xs_t[d][wave * 32 + quad * 4];
            floatx4 xv1 = *(const floatx4*)&xs_t[d][wave * 32 + 16 + quad * 4];
#pragma unroll
            for (int reg = 0; reg < 4; ++reg) {
                emb_acc[0][reg] = fmaf(xv0[reg], fmaxf(acc0[reg], 0.f), emb_acc[0][reg]);
                emb_acc[1][reg] = fmaf(xv1[reg], fmaxf(acc1[reg], 0.f), emb_acc[1][reg]);
            }
        }
        if (have) {   // write-late into the other buffer
#pragma unroll
            for (int ci = 0; ci < 2; ++ci) {
                int c = wave * 2 + ci, dt = c >> 2, kt = c & 3;
                half8 v;
#pragma unroll
                for (int e = 0; e < 8; ++e) v[e] = (_Float16)g[ci * 8 + e];
                *(half8*)&Bs[cb ^ 1][dt][kt][lane * 8] = v;
            }
        }
        __syncthreads();   // single barrier per iter
    }

    // epilogue: tanh -> embf; each 16-row tile = one batch -> mean direct
#pragma unroll
    for (int t = 0; t < 2; ++t) {
        float e[4];
#pragma unroll
        for (int reg = 0; reg < 4; ++reg) {
            e[reg] = tanhf(emb_acc[t][reg]);
            embf[(size_t)(n0 + wave * 32 + t * 16 + quad * 4 + reg) * HID + j0 + l15] =
                (_Float16)e[reg];
        }
        float s = e[0] + e[1] + e[2] + e[3];
        s += __shfl_xor(s, 16, 64);
        s += __shfl_xor(s, 32, 64);
        if (quad == 0)
            emeanf[(size_t)(rt * 8 + wave * 2 + t) * HID + j0 + l15] =
                (_Float16)(s * (1.f / 16));
    }
}

// ---------------------------------------------------------------------------
// Kernel T (fused tail), 512 blocks x 16 rows (1 softmax group each):
//   vals = relu(relu(emb@vw1+b)@vw2+b)                 [MFMA, regs]
//   scores = relu(relu([emb|mean]@aw1+b)@aw2+b)@aw3+b  [MFMA + dot]
//   att = softmax over the 16 rows; out[g] = sum_a att*vals (direct store)
// ---------------------------------------------------------------------------
__global__ __launch_bounds__(512, 4)
void k_tail(const _Float16* __restrict__ embf, const _Float16* __restrict__ emeanf,
            const _Float16* __restrict__ vw1p, const float* __restrict__ vb1,
            const _Float16* __restrict__ vw2p, const float* __restrict__ vb2,
            const _Float16* __restrict__ aw1p, const float* __restrict__ ab1,
            const _Float16* __restrict__ aw2p, const float* __restrict__ ab2,
            const float* __restrict__ aw3, const float* __restrict__ ab3,
            float* __restrict__ out) {
    __shared__ _Float16 embs[16][LSTR];
    __shared__ _Float16 means[16][LSTR];
    __shared__ _Float16 tAs[16][LSTR];
    __shared__ _Float16 tBs[16][LSTR];
    __shared__ float scr[16][32];
    __shared__ float satt[16];
    __shared__ float att[16];
    int g = blockIdx.x;       // batch 0..511
    int n0 = g * 16;
    int tid = threadIdx.x;
    int wave = tid >> 6, lane = tid & 63, l15 = lane & 15, quad = lane >> 4;
    int ct = wave;            // wave owns col-tile ct of 8

    {   // stage emb rows + mean rows (512 half8 loads = 1/thread)
        int m = tid >> 8, r = (tid >> 4) & 15, c8 = (tid & 15) * 8;
        if (m == 0)
            *(half8*)&embs[r][c8] = *(const half8*)(embf + (size_t)(n0 + r) * HID + c8);
        else
            // mean_rep[n] = emb_mean[n % 512] (torch .repeat tiling) — exact.
            *(half8*)&means[r][c8] =
                *(const half8*)(emeanf + (size_t)((n0 & 511) + r) * HID + c8);
    }
    __syncthreads();

    half8 av[4], amean[4];
#pragma unroll
    for (int ks = 0; ks < 4; ++ks) {
        av[ks]    = *(const half8*)&embs[l15][ks * 32 + quad * 8];
        amean[ks] = *(const half8*)&means[l15][ks * 32 + quad * 8];
    }

    // ---- v1: t1 = relu(emb @ vw1 + vb1) ----
    floatx4 acc;
    {
        float bb = vb1[ct * 16 + l15];
        acc = (floatx4){bb, bb, bb, bb};
    }
#pragma unroll
    for (int ks = 0; ks < 4; ++ks) {
        half8 bfr = *(const half8*)(vw1p + ((size_t)ct * 4 + ks) * 512 + lane * 8);
        acc = __builtin_amdgcn_mfma_f32_16x16x32_f16(av[ks], bfr, acc, 0, 0, 0);
    }
#pragma unroll
    for (int reg = 0; reg < 4; ++reg)
        tAs[quad * 4 + reg][ct * 16 + l15] = (_Float16)fmaxf(acc[reg], 0.f);
    __syncthreads();

    half8 at[4];
#pragma unroll
    for (int ks = 0; ks < 4; ++ks)
        at[ks] = *(const half8*)&tAs[l15][ks * 32 + quad * 8];

    // ---- v2: vals = relu(t1 @ vw2 + vb2), kept in registers ----
    floatx4 vacc;
    {
        float bb = vb2[ct * 16 + l15];
        vacc = (floatx4){bb, bb, bb, bb};
    }
#pragma unroll
    for (int ks = 0; ks < 4; ++ks) {
        half8 bfr = *(const half8*)(vw2p + ((size_t)ct * 4 + ks) * 512 + lane * 8);
        vacc = __builtin_amdgcn_mfma_f32_16x16x32_f16(at[ks], bfr, vacc, 0, 0, 0);
    }

    // ---- a1: ta1 = relu([emb|mean] @ aw1 + ab1), K=256 ----
    floatx4 aacc;
    {
        float bb = ab1[ct * 16 + l15];
        aacc = (floatx4){bb, bb, bb, bb};
    }
#pragma unroll
    for (int ks = 0; ks < 8; ++ks) {
        half8 bfr = *(const half8*)(aw1p + ((size_t)ct * 8 + ks) * 512 + lane * 8);
        half8 a = (ks < 4) ? av[ks] : amean[ks - 4];
        aacc = __builtin_amdgcn_mfma_f32_16x16x32_f16(a, bfr, aacc, 0, 0, 0);
    }
#pragma unroll
    for (int reg = 0; reg < 4; ++reg)
        tBs[quad * 4 + reg][ct * 16 + l15] = (_Float16)fmaxf(aacc[reg], 0.f);
    __syncthreads();

    half8 aa[4];
#pragma unroll
    for (int ks = 0; ks < 4; ++ks)
        aa[ks] = *(const half8*)&tBs[l15][ks * 32 + quad * 8];

    // ---- a2: t2 = relu(ta1 @ aw2 + ab2) -> tAs ----
    floatx4 a2acc;
    {
        float bb = ab2[ct * 16 + l15];
        a2acc = (floatx4){bb, bb, bb, bb};
    }
#pragma unroll
    for (int ks = 0; ks < 4; ++ks) {
        half8 bfr = *(const half8*)(aw2p + ((size_t)ct * 4 + ks) * 512 + lane * 8);
        a2acc = __builtin_amdgcn_mfma_f32_16x16x32_f16(aa[ks], bfr, a2acc, 0, 0, 0);
    }
    __syncthreads();   // everyone done reading tAs (at) from v1 stage
#pragma unroll
    for (int reg = 0; reg < 4; ++reg)
        tAs[quad * 4 + reg][ct * 16 + l15] = (_Float16)fmaxf(a2acc[reg], 0.f);
    __syncthreads();

    // ---- scores: s[r] = t2[r,:] . aw3 + ab3 ----
    {
        int r = tid >> 5, ch = tid & 31;
        float p = 0.f;
#pragma unroll
        for (int k = 0; k < 4; ++k)
            p += (float)tAs[r][ch * 4 + k] * aw3[ch * 4 + k];
        scr[r][ch] = p;
    }
    __syncthreads();
    if (tid < 16) {
        float s = ab3[0];
#pragma unroll
        for (int ch = 0; ch < 32; ++ch) s += scr[tid][ch];
        satt[tid] = s;
    }
    __syncthreads();
    if (tid < 16) {
        float m = -1e30f;
#pragma unroll
        for (int a = 0; a < 16; ++a) m = fmaxf(m, satt[a]);
        float S = 0.f;
#pragma unroll
        for (int a = 0; a < 16; ++a) S += expf(satt[a] - m);
        att[tid] = expf(satt[tid] - m) / S;
    }
    __syncthreads();

    // ---- weighted sum: out[g, col] = sum_a att[a] * vals[a, col] ----
    {
        float p = 0.f;
#pragma unroll
        for (int reg = 0; reg < 4; ++reg)
            p += att[quad * 4 + reg] * fmaxf(vacc[reg], 0.f);
        p += __shfl_xor(p, 16, 64);
        p += __shfl_xor(p, 32, 64);
        if (quad == 0) out[(size_t)g * HID + ct * 16 + l15] = p;
    }
}

// ---------------------------------------------------------------------------
extern "C" void kernel_launch(void* const* d_in, const int* in_sizes, int n_in,
                              void* d_out, int out_size, void* d_ws, size_t ws_size,
                              hipStream_t stream) {
    const float* obs = (const float*)d_in[0];
    const float* lat = (const float*)d_in[1];
    const float* hw1 = (const float*)d_in[2];
    const float* hb1 = (const float*)d_in[3];
    const float* hw2 = (const float*)d_in[4];
    const float* hb2 = (const float*)d_in[5];
    const float* vw1 = (const float*)d_in[6];
    const float* vb1 = (const float*)d_in[7];
    const float* vw2 = (const float*)d_in[8];
    const float* vb2 = (const float*)d_in[9];
    const float* aw1 = (const float*)d_in[10];
    const float* ab1 = (const float*)d_in[11];
    const float* aw2 = (const float*)d_in[12];
    const float* ab2 = (const float*)d_in[13];
    const float* aw3 = (const float*)d_in[14];
    const float* ab3 = (const float*)d_in[15];
    float* out = (float*)d_out;

    char* ws = (char*)d_ws;
    _Float16*  embf   = (_Float16*)ws;  ws += (size_t)NROWS * HID * 2;     // 2 MB
    _Float16*  emeanf = (_Float16*)ws;  ws += (size_t)BATCH * HID * 2;     // 128 KB
    _Float16*  vw1p   = (_Float16*)ws;  ws += (size_t)HID * HID * 2;       // 32 KB
    _Float16*  vw2p   = (_Float16*)ws;  ws += (size_t)HID * HID * 2;
    _Float16*  aw1p   = (_Float16*)ws;  ws += (size_t)2 * HID * HID * 2;   // 64 KB
    _Float16*  aw2p   = (_Float16*)ws;  ws += (size_t)HID * HID * 2;

    hipLaunchKernelGGL(k_main, dim3(532), dim3(256), 0, stream,
                       obs, lat, hw1, hb1, hw2, hb2, vw1, vw2, aw1, aw2,
                       embf, emeanf, vw1p, vw2p, aw1p, aw2p);
    hipLaunchKernelGGL(k_tail, dim3(BATCH), dim3(512), 0, stream,
                       embf, emeanf, vw1p, vb1, vw2p, vb2,
                       aw1p, ab1, aw2p, ab2, aw3, ab3, out);
}

// Round 5
// 133.878 us; speedup vs baseline: 1.6659x; 1.0317x over previous
//
#include <hip/hip_runtime.h>
#include <hip/hip_bf16.h>
#include <math.h>

// Problem constants (fixed by setup_inputs)
#define BATCH 512
#define NADV  16
#define NROWS (BATCH*NADV)     // 8192
#define DS    32
#define DO    32
#define DIM   64               // DS + DO
#define HID   128
#define WCOLS (DIM*HID)        // 8192 columns of hw2
#define LSTR  136              // padded f16 LDS row stride (2-way bank aliasing)

typedef _Float16 half8 __attribute__((ext_vector_type(8)));
typedef float floatx4 __attribute__((ext_vector_type(4)));

__device__ inline void async_ld16(void* lds, const void* g) {
    __builtin_amdgcn_global_load_lds(
        (const __attribute__((address_space(1))) void*)g,
        (__attribute__((address_space(3))) void*)lds, 16, 0, 0);
}

// ---------------------------------------------------------------------------
// Kernel PREP: 256 blocks pack hw2 (f32) -> w2p (f16, MFMA-native chunks).
// chunk(ct,kt)[lane*8+e] = hw2[kt*32+(lane>>4)*8+e][ct*16+(lane&15)]
// so a wave's B-fragment load is ONE contiguous 1 KB burst.
// ---------------------------------------------------------------------------
__global__ __launch_bounds__(256)
void k_prep(const float* __restrict__ hw2, _Float16* __restrict__ w2p) {
    __shared__ __align__(16) float smem[32 * 132];
    int b = blockIdx.x, tid = threadIdx.x;
    int jb = b >> 2, kt = b & 3;
    for (int i = tid; i < 32 * 32; i += 256) {
        int r = i >> 5, c4 = (i & 31) * 4;
        *(float4*)&smem[r * 132 + c4] =
            *(const float4*)(hw2 + (size_t)(kt * 32 + r) * WCOLS + jb * 128 + c4);
    }
    __syncthreads();
    for (int i = tid; i < 8 * 64; i += 256) {
        int ctl = i >> 6, ln = i & 63;
        int ct = jb * 8 + ctl;
        int rbase = (ln >> 4) * 8, cc = ctl * 16 + (ln & 15);
        half8 v;
#pragma unroll
        for (int e = 0; e < 8; ++e) v[e] = (_Float16)smem[(rbase + e) * 132 + cc];
        *(half8*)(w2p + ((size_t)ct * 4 + kt) * 512 + ln * 8) = v;
    }
}

// ---------------------------------------------------------------------------
// Kernel MAIN: grid 532 x 256 threads (4 waves).
//  Blocks [0,512): hyper GEMM, block = 128 rows x 16 emb-cols x all 64 d.
//   - in-block h = relu(x@hw1+hb1) via MFMA -> hscr (LDS), then EVERY wave
//     loads A-frags for ALL 128 rows (32 half8 = 128 VGPR) -> full-M.
//   - each wave owns a PRIVATE set of 16 d-values; stages its own packed-f16
//     B-tiles via global_load_lds (depth-2 double buffer) and consumes them
//     with counted `s_waitcnt vmcnt(4)` — NO __syncthreads in the main loop.
//     Per B-fragment ds_read: 8 MFMAs (R=8 reuse) -> LDS pipe ~9k cyc/CU.
//   - epilogue: cross-wave d-reduction in LDS (reuses xs_t region), tanh,
//     embf store + per-batch mean direct.
//  Blocks [512,532): pack small tail weights (vw1,vw2,aw1,aw2) for k_tail.
// LDS 71680 B -> 2 blocks/CU; ~210 VGPR -> 8 waves/CU.
// ---------------------------------------------------------------------------
__global__ __launch_bounds__(256, 2)
void k_main(const float* __restrict__ obs, const float* __restrict__ latent,
            const float* __restrict__ hw1, const float* __restrict__ hb1,
            const float* __restrict__ hb2, const _Float16* __restrict__ w2p,
            const float* __restrict__ vw1, const float* __restrict__ vw2,
            const float* __restrict__ aw1, const float* __restrict__ aw2,
            _Float16* __restrict__ embf, _Float16* __restrict__ emeanf,
            _Float16* __restrict__ vw1p, _Float16* __restrict__ vw2p,
            _Float16* __restrict__ aw1p, _Float16* __restrict__ aw2p) {
    // LDS map (71680 B):
    //   [0,33792)      xs_t[64][132] f32 (loop) -> red[4][128][16] f32 (epilogue)
    //   [33792,67584)  hscr[128][132] f16 (pre-loop) -> Bs[4][2][4][512] f16 (loop)
    //   [67584,71680)  bias_s[64*16] f32
    __shared__ __align__(16) char smraw[71680];
    int b   = blockIdx.x;
    int tid = threadIdx.x;
    int wave = tid >> 6, lane = tid & 63, l15 = lane & 15, quad = lane >> 4;

    if (b >= 512) {
        // -------- small-weight pack (20 units) --------
        float* smem = (float*)smraw;
        int u = b - 512;
        const float* src; _Float16* dst; int Kt, kt;
        if (u < 4)       { src = vw1; dst = vw1p; Kt = 4; kt = u; }
        else if (u < 8)  { src = vw2; dst = vw2p; Kt = 4; kt = u - 4; }
        else if (u < 16) { src = aw1; dst = aw1p; Kt = 8; kt = u - 8; }
        else             { src = aw2; dst = aw2p; Kt = 4; kt = u - 16; }
        for (int i = tid; i < 32 * 32; i += 256) {
            int r = i >> 5, c4 = (i & 31) * 4;
            *(float4*)&smem[r * 132 + c4] =
                *(const float4*)(src + (size_t)(kt * 32 + r) * HID + c4);
        }
        __syncthreads();
        for (int i = tid; i < 8 * 64; i += 256) {
            int ctl = i >> 6, ln = i & 63;
            int rbase = (ln >> 4) * 8, cc = ctl * 16 + (ln & 15);
            half8 v;
#pragma unroll
            for (int e = 0; e < 8; ++e) v[e] = (_Float16)smem[(rbase + e) * 132 + cc];
            *(half8*)(dst + ((size_t)ctl * Kt + kt) * 512 + ln * 8) = v;
        }
        return;
    }

    // -------- hyper GEMM block --------
    float (*xs_t)[132] = (float(*)[132])smraw;
    _Float16* hscr = (_Float16*)(smraw + 33792);                   // [128][132]
    _Float16 (*Bs)[2][4][512] = (_Float16(*)[2][4][512])(smraw + 33792);
    float* bias_s = (float*)(smraw + 67584);

    int jt = b & 7;          // emb col-tile (16 cols) — XCD-aligned B reuse
    int rt = b >> 3;         // row-tile: rows [rt*128, +128)
    int n0 = rt * 128;
    int j0 = jt * 16;

    // stage x TRANSPOSED (obs[n%512] ++ latent[n]) and bias slice
    for (int i = tid; i < 128 * 16; i += 256) {
        int r = i >> 4, c4 = (i & 15) * 4;
        float4 v;
        if (c4 < DS) v = *(const float4*)(obs + ((n0 + r) & (BATCH - 1)) * DS + c4);
        else         v = *(const float4*)(latent + (size_t)(n0 + r) * DO + (c4 - DS));
        xs_t[c4 + 0][r] = v.x;
        xs_t[c4 + 1][r] = v.y;
        xs_t[c4 + 2][r] = v.z;
        xs_t[c4 + 3][r] = v.w;
    }
    for (int i = tid; i < 64 * 16; i += 256)
        bias_s[i] = hb2[(i >> 4) * HID + j0 + (i & 15)];

    // ---- in-block h = relu(x @ hw1 + hb1): wave computes rows w*32..+32 ----
    {
        half8 afx[2][2];
#pragma unroll
        for (int t = 0; t < 2; ++t) {
            int n = n0 + wave * 32 + t * 16 + l15;
            const float* orow = obs + (size_t)(n & (BATCH - 1)) * DS + quad * 8;
            const float* lrow = latent + (size_t)n * DO + quad * 8;
#pragma unroll
            for (int e = 0; e < 8; ++e) {
                afx[t][0][e] = (_Float16)orow[e];
                afx[t][1][e] = (_Float16)lrow[e];
            }
        }
#pragma unroll
        for (int ct = 0; ct < 8; ++ct) {
            half8 bf[2];
#pragma unroll
            for (int ks = 0; ks < 2; ++ks) {
                const float* wsrc = hw1 + (size_t)(ks * 32 + quad * 8) * HID + ct * 16 + l15;
#pragma unroll
                for (int e = 0; e < 8; ++e) bf[ks][e] = (_Float16)wsrc[(size_t)e * HID];
            }
            float bb = hb1[ct * 16 + l15];
#pragma unroll
            for (int t = 0; t < 2; ++t) {
                floatx4 acc = {bb, bb, bb, bb};
#pragma unroll
                for (int ks = 0; ks < 2; ++ks)
                    acc = __builtin_amdgcn_mfma_f32_16x16x32_f16(afx[t][ks], bf[ks], acc, 0, 0, 0);
#pragma unroll
                for (int reg = 0; reg < 4; ++reg)
                    hscr[(wave * 32 + t * 16 + quad * 4 + reg) * 132 + ct * 16 + l15] =
                        (_Float16)fmaxf(acc[reg], 0.f);
            }
        }
    }
    __syncthreads();   // hscr complete (also xs_t/bias staged)

    // ---- full-M A-frags: all 128 rows, 32 half8 = 128 VGPR ----
    half8 af[8][4];
#pragma unroll
    for (int t = 0; t < 8; ++t)
#pragma unroll
        for (int ks = 0; ks < 4; ++ks)
            af[t][ks] = *(const half8*)&hscr[(t * 16 + l15) * 132 + ks * 32 + quad * 8];
    __syncthreads();   // all A-reads done; Bs may overwrite hscr region

    // ---- main loop: wave-private d set, depth-2 pipeline, NO barriers ----
    // wave w, step i (0..15): d = (i>>1)*8 + w*2 + (i&1), buffer i&1.
    // w2p chunk base for (d, jt): d*16384 + jt*2048 + kt*512.
    float emb_acc[8][4];
#pragma unroll
    for (int t = 0; t < 8; ++t)
#pragma unroll
        for (int reg = 0; reg < 4; ++reg) emb_acc[t][reg] = 0.f;

    const _Float16* wsrc0 = w2p + (size_t)jt * 2048 + lane * 8;
    auto STAGE = [&](int d, int buf) {
        const _Float16* src = wsrc0 + (size_t)d * 16384;
        _Float16* dst = &Bs[wave][buf][0][0];
#pragma unroll
        for (int kt = 0; kt < 4; ++kt)
            async_ld16(dst + kt * 512, src + kt * 512);
    };
    STAGE(wave * 2, 0);
    STAGE(wave * 2 + 1, 1);

    for (int i = 0; i < 16; ++i) {
        if (i < 15) asm volatile("s_waitcnt vmcnt(4)" ::: "memory");
        else        asm volatile("s_waitcnt vmcnt(0)" ::: "memory");
        __builtin_amdgcn_sched_barrier(0);
        int d = (i >> 1) * 8 + wave * 2 + (i & 1);
        int buf = i & 1;
        half8 bfr0 = *(const half8*)&Bs[wave][buf][0][lane * 8];
        half8 bfr1 = *(const half8*)&Bs[wave][buf][1][lane * 8];
        half8 bfr2 = *(const half8*)&Bs[wave][buf][2][lane * 8];
        half8 bfr3 = *(const half8*)&Bs[wave][buf][3][lane * 8];
        float bb = bias_s[d * 16 + l15];
#pragma unroll
        for (int t = 0; t < 8; ++t) {
            floatx4 acc = {bb, bb, bb, bb};
            acc = __builtin_amdgcn_mfma_f32_16x16x32_f16(af[t][0], bfr0, acc, 0, 0, 0);
            acc = __builtin_amdgcn_mfma_f32_16x16x32_f16(af[t][1], bfr1, acc, 0, 0, 0);
            acc = __builtin_amdgcn_mfma_f32_16x16x32_f16(af[t][2], bfr2, acc, 0, 0, 0);
            acc = __builtin_amdgcn_mfma_f32_16x16x32_f16(af[t][3], bfr3, acc, 0, 0, 0);
            floatx4 xv = *(const floatx4*)&xs_t[d][t * 16 + quad * 4];
#pragma unroll
            for (int reg = 0; reg < 4; ++reg)
                emb_acc[t][reg] = fmaf(xv[reg], fmaxf(acc[reg], 0.f), emb_acc[t][reg]);
        }
        if (i + 2 < 16) STAGE(d + 8, buf);   // same buffer, just consumed
    }
    __syncthreads();   // all waves done with xs_t; safe to reuse as red[]

    // ---- cross-wave d-reduction + tanh + mean ----
    float* red = (float*)smraw;   // [4][128][16]
#pragma unroll
    for (int t = 0; t < 8; ++t)
#pragma unroll
        for (int reg = 0; reg < 4; ++reg)
            red[((wave * 128) + t * 16 + quad * 4 + reg) * 16 + l15] = emb_acc[t][reg];
    __syncthreads();
#pragma unroll
    for (int t2 = 0; t2 < 2; ++t2) {
        float e[4];
#pragma unroll
        for (int rr = 0; rr < 4; ++rr) {
            int row = wave * 32 + t2 * 16 + quad * 4 + rr;
            float s = red[(0 * 128 + row) * 16 + l15] + red[(1 * 128 + row) * 16 + l15]
                    + red[(2 * 128 + row) * 16 + l15] + red[(3 * 128 + row) * 16 + l15];
            e[rr] = tanhf(s);
            embf[(size_t)(n0 + row) * HID + j0 + l15] = (_Float16)e[rr];
        }
        float m = e[0] + e[1] + e[2] + e[3];
        m += __shfl_xor(m, 16, 64);
        m += __shfl_xor(m, 32, 64);
        if (quad == 0)
            emeanf[(size_t)(rt * 8 + wave * 2 + t2) * HID + j0 + l15] =
                (_Float16)(m * (1.f / 16));
    }
}

// ---------------------------------------------------------------------------
// Kernel T (fused tail), 512 blocks x 16 rows (1 softmax group each):
//   vals = relu(relu(emb@vw1+b)@vw2+b)                 [MFMA, regs]
//   scores = relu(relu([emb|mean]@aw1+b)@aw2+b)@aw3+b  [MFMA + dot]
//   att = softmax over the 16 rows; out[g] = sum_a att*vals (direct store)
// ---------------------------------------------------------------------------
__global__ __launch_bounds__(512, 4)
void k_tail(const _Float16* __restrict__ embf, const _Float16* __restrict__ emeanf,
            const _Float16* __restrict__ vw1p, const float* __restrict__ vb1,
            const _Float16* __restrict__ vw2p, const float* __restrict__ vb2,
            const _Float16* __restrict__ aw1p, const float* __restrict__ ab1,
            const _Float16* __restrict__ aw2p, const float* __restrict__ ab2,
            const float* __restrict__ aw3, const float* __restrict__ ab3,
            float* __restrict__ out) {
    __shared__ _Float16 embs[16][LSTR];
    __shared__ _Float16 means[16][LSTR];
    __shared__ _Float16 tAs[16][LSTR];
    __shared__ _Float16 tBs[16][LSTR];
    __shared__ float scr[16][32];
    __shared__ float satt[16];
    __shared__ float att[16];
    int g = blockIdx.x;       // batch 0..511
    int n0 = g * 16;
    int tid = threadIdx.x;
    int wave = tid >> 6, lane = tid & 63, l15 = lane & 15, quad = lane >> 4;
    int ct = wave;            // wave owns col-tile ct of 8

    {   // stage emb rows + mean rows (512 half8 loads = 1/thread)
        int m = tid >> 8, r = (tid >> 4) & 15, c8 = (tid & 15) * 8;
        if (m == 0)
            *(half8*)&embs[r][c8] = *(const half8*)(embf + (size_t)(n0 + r) * HID + c8);
        else
            // mean_rep[n] = emb_mean[n % 512] (torch .repeat tiling) — exact.
            *(half8*)&means[r][c8] =
                *(const half8*)(emeanf + (size_t)((n0 & 511) + r) * HID + c8);
    }
    __syncthreads();

    half8 av[4], amean[4];
#pragma unroll
    for (int ks = 0; ks < 4; ++ks) {
        av[ks]    = *(const half8*)&embs[l15][ks * 32 + quad * 8];
        amean[ks] = *(const half8*)&means[l15][ks * 32 + quad * 8];
    }

    // ---- v1: t1 = relu(emb @ vw1 + vb1) ----
    floatx4 acc;
    {
        float bb = vb1[ct * 16 + l15];
        acc = (floatx4){bb, bb, bb, bb};
    }
#pragma unroll
    for (int ks = 0; ks < 4; ++ks) {
        half8 bfr = *(const half8*)(vw1p + ((size_t)ct * 4 + ks) * 512 + lane * 8);
        acc = __builtin_amdgcn_mfma_f32_16x16x32_f16(av[ks], bfr, acc, 0, 0, 0);
    }
#pragma unroll
    for (int reg = 0; reg < 4; ++reg)
        tAs[quad * 4 + reg][ct * 16 + l15] = (_Float16)fmaxf(acc[reg], 0.f);
    __syncthreads();

    half8 at[4];
#pragma unroll
    for (int ks = 0; ks < 4; ++ks)
        at[ks] = *(const half8*)&tAs[l15][ks * 32 + quad * 8];

    // ---- v2: vals = relu(t1 @ vw2 + vb2), kept in registers ----
    floatx4 vacc;
    {
        float bb = vb2[ct * 16 + l15];
        vacc = (floatx4){bb, bb, bb, bb};
    }
#pragma unroll
    for (int ks = 0; ks < 4; ++ks) {
        half8 bfr = *(const half8*)(vw2p + ((size_t)ct * 4 + ks) * 512 + lane * 8);
        vacc = __builtin_amdgcn_mfma_f32_16x16x32_f16(at[ks], bfr, vacc, 0, 0, 0);
    }

    // ---- a1: ta1 = relu([emb|mean] @ aw1 + ab1), K=256 ----
    floatx4 aacc;
    {
        float bb = ab1[ct * 16 + l15];
        aacc = (floatx4){bb, bb, bb, bb};
    }
#pragma unroll
    for (int ks = 0; ks < 8; ++ks) {
        half8 bfr = *(const half8*)(aw1p + ((size_t)ct * 8 + ks) * 512 + lane * 8);
        half8 a = (ks < 4) ? av[ks] : amean[ks - 4];
        aacc = __builtin_amdgcn_mfma_f32_16x16x32_f16(a, bfr, aacc, 0, 0, 0);
    }
#pragma unroll
    for (int reg = 0; reg < 4; ++reg)
        tBs[quad * 4 + reg][ct * 16 + l15] = (_Float16)fmaxf(aacc[reg], 0.f);
    __syncthreads();

    half8 aa[4];
#pragma unroll
    for (int ks = 0; ks < 4; ++ks)
        aa[ks] = *(const half8*)&tBs[l15][ks * 32 + quad * 8];

    // ---- a2: t2 = relu(ta1 @ aw2 + ab2) -> tAs ----
    floatx4 a2acc;
    {
        float bb = ab2[ct * 16 + l15];
        a2acc = (floatx4){bb, bb, bb, bb};
    }
#pragma unroll
    for (int ks = 0; ks < 4; ++ks) {
        half8 bfr = *(const half8*)(aw2p + ((size_t)ct * 4 + ks) * 512 + lane * 8);
        a2acc = __builtin_amdgcn_mfma_f32_16x16x32_f16(aa[ks], bfr, a2acc, 0, 0, 0);
    }
    __syncthreads();   // everyone done reading tAs (at) from v1 stage
#pragma unroll
    for (int reg = 0; reg < 4; ++reg)
        tAs[quad * 4 + reg][ct * 16 + l15] = (_Float16)fmaxf(a2acc[reg], 0.f);
    __syncthreads();

    // ---- scores: s[r] = t2[r,:] . aw3 + ab3 ----
    {
        int r = tid >> 5, ch = tid & 31;
        float p = 0.f;
#pragma unroll
        for (int k = 0; k < 4; ++k)
            p += (float)tAs[r][ch * 4 + k] * aw3[ch * 4 + k];
        scr[r][ch] = p;
    }
    __syncthreads();
    if (tid < 16) {
        float s = ab3[0];
#pragma unroll
        for (int ch = 0; ch < 32; ++ch) s += scr[tid][ch];
        satt[tid] = s;
    }
    __syncthreads();
    if (tid < 16) {
        float m = -1e30f;
#pragma unroll
        for (int a = 0; a < 16; ++a) m = fmaxf(m, satt[a]);
        float S = 0.f;
#pragma unroll
        for (int a = 0; a < 16; ++a) S += expf(satt[a] - m);
        att[tid] = expf(satt[tid] - m) / S;
    }
    __syncthreads();

    // ---- weighted sum: out[g, col] = sum_a att[a] * vals[a, col] ----
    {
        float p = 0.f;
#pragma unroll
        for (int reg = 0; reg < 4; ++reg)
            p += att[quad * 4 + reg] * fmaxf(vacc[reg], 0.f);
        p += __shfl_xor(p, 16, 64);
        p += __shfl_xor(p, 32, 64);
        if (quad == 0) out[(size_t)g * HID + ct * 16 + l15] = p;
    }
}

// ---------------------------------------------------------------------------
extern "C" void kernel_launch(void* const* d_in, const int* in_sizes, int n_in,
                              void* d_out, int out_size, void* d_ws, size_t ws_size,
                              hipStream_t stream) {
    const float* obs = (const float*)d_in[0];
    const float* lat = (const float*)d_in[1];
    const float* hw1 = (const float*)d_in[2];
    const float* hb1 = (const float*)d_in[3];
    const float* hw2 = (const float*)d_in[4];
    const float* hb2 = (const float*)d_in[5];
    const float* vw1 = (const float*)d_in[6];
    const float* vb1 = (const float*)d_in[7];
    const float* vw2 = (const float*)d_in[8];
    const float* vb2 = (const float*)d_in[9];
    const float* aw1 = (const float*)d_in[10];
    const float* ab1 = (const float*)d_in[11];
    const float* aw2 = (const float*)d_in[12];
    const float* ab2 = (const float*)d_in[13];
    const float* aw3 = (const float*)d_in[14];
    const float* ab3 = (const float*)d_in[15];
    float* out = (float*)d_out;

    char* ws = (char*)d_ws;
    _Float16*  embf   = (_Float16*)ws;  ws += (size_t)NROWS * HID * 2;     // 2 MB
    _Float16*  w2p    = (_Float16*)ws;  ws += (size_t)WCOLS * HID * 2;     // 2 MB
    _Float16*  emeanf = (_Float16*)ws;  ws += (size_t)BATCH * HID * 2;     // 128 KB
    _Float16*  vw1p   = (_Float16*)ws;  ws += (size_t)HID * HID * 2;       // 32 KB
    _Float16*  vw2p   = (_Float16*)ws;  ws += (size_t)HID * HID * 2;
    _Float16*  aw1p   = (_Float16*)ws;  ws += (size_t)2 * HID * HID * 2;   // 64 KB
    _Float16*  aw2p   = (_Float16*)ws;  ws += (size_t)HID * HID * 2;

    hipLaunchKernelGGL(k_prep, dim3(256), dim3(256), 0, stream, hw2, w2p);
    hipLaunchKernelGGL(k_main, dim3(532), dim3(256), 0, stream,
                       obs, lat, hw1, hb1, hb2, w2p, vw1, vw2, aw1, aw2,
                       embf, emeanf, vw1p, vw2p, aw1p, aw2p);
    hipLaunchKernelGGL(k_tail, dim3(BATCH), dim3(512), 0, stream,
                       embf, emeanf, vw1p, vb1, vw2p, vb2,
                       aw1p, ab1, aw2p, ab2, aw3, ab3, out);
}

// Round 6
// 131.977 us; speedup vs baseline: 1.6899x; 1.0144x over previous
//
#include <hip/hip_runtime.h>
#include <hip/hip_bf16.h>
#include <math.h>

// Problem constants (fixed by setup_inputs)
#define BATCH 512
#define NADV  16
#define NROWS (BATCH*NADV)     // 8192
#define DS    32
#define DO    32
#define DIM   64               // DS + DO
#define HID   128
#define WCOLS (DIM*HID)        // 8192 columns of hw2
#define LSTR  136              // padded f16 LDS row stride (2-way bank aliasing)
#define PACK_BLOCKS 276

typedef _Float16 half8 __attribute__((ext_vector_type(8)));
typedef float floatx4 __attribute__((ext_vector_type(4)));

__device__ inline void async_ld16(void* lds, const void* g) {
    __builtin_amdgcn_global_load_lds(
        (const __attribute__((address_space(1))) void*)g,
        (__attribute__((address_space(3))) void*)lds, 16, 0, 0);
}

// xs_t row-swizzle: spreads the transpose-staging scalar writes across banks
// (2-way instead of 16-way) while keeping float4 reads 16B-aligned.
#define XSW(c) ((((c) >> 2) & 7) << 2)

// ---------------------------------------------------------------------------
// Kernel PREP (fused): blocks [0,276) pack weights into MFMA-native f16
// chunks; blocks [276,788) build h = relu(x@hw1+hb1) via MFMA (A-frag from
// obs/latent f32->f16 in regs; B-frag gathered from L1-hot hw1) -> hf.
// Packed layout: chunk(ct,kt)[lane*8+e] = W[kt*32+(lane>>4)*8+e][ct*16+(lane&15)]
// ---------------------------------------------------------------------------
__global__ __launch_bounds__(256)
void k_prep(const float* __restrict__ obs, const float* __restrict__ latent,
            const float* __restrict__ hw1, const float* __restrict__ hb1,
            const float* __restrict__ hw2, const float* __restrict__ vw1,
            const float* __restrict__ vw2, const float* __restrict__ aw1,
            const float* __restrict__ aw2,
            _Float16* __restrict__ hf,
            _Float16* __restrict__ w2p, _Float16* __restrict__ vw1p,
            _Float16* __restrict__ vw2p, _Float16* __restrict__ aw1p,
            _Float16* __restrict__ aw2p) {
    __shared__ __align__(16) float smem[32 * 132];   // 16.9 KB
    int b = blockIdx.x;
    int tid = threadIdx.x;
    if (b < PACK_BLOCKS) {
        const float* src; _Float16* dst; int N, Kt, jb, kt;
        if (b < 256)      { src = hw2; dst = w2p;  N = WCOLS; Kt = 4; jb = b >> 2; kt = b & 3; }
        else if (b < 260) { src = vw1; dst = vw1p; N = HID;   Kt = 4; jb = 0; kt = b - 256; }
        else if (b < 264) { src = vw2; dst = vw2p; N = HID;   Kt = 4; jb = 0; kt = b - 260; }
        else if (b < 272) { src = aw1; dst = aw1p; N = HID;   Kt = 8; jb = 0; kt = b - 264; }
        else              { src = aw2; dst = aw2p; N = HID;   Kt = 4; jb = 0; kt = b - 272; }
        for (int i = tid; i < 32 * 32; i += 256) {
            int r = i >> 5, c4 = (i & 31) * 4;
            *(float4*)&smem[r * 132 + c4] =
                *(const float4*)(src + (size_t)(kt * 32 + r) * N + jb * 128 + c4);
        }
        __syncthreads();
        for (int i = tid; i < 8 * 64; i += 256) {
            int ctl = i >> 6, ln = i & 63;
            int ct = jb * 8 + ctl;
            int rbase = (ln >> 4) * 8, cc = ctl * 16 + (ln & 15);
            half8 v;
#pragma unroll
            for (int e = 0; e < 8; ++e) v[e] = (_Float16)smem[(rbase + e) * 132 + cc];
            *(half8*)(dst + ((size_t)ct * Kt + kt) * 512 + ln * 8) = v;
        }
    } else {
        // h = relu(x @ hw1 + hb1) via MFMA: 16 rows, 4 waves x 2 col-tiles
        int n0 = (b - PACK_BLOCKS) * 16;
        int wave = tid >> 6, lane = tid & 63, l15 = lane & 15, quad = lane >> 4;
        half8 af2[2];
        {
            int n = n0 + l15;
            const float* orow = obs + (size_t)(n & (BATCH - 1)) * DS + quad * 8;
            const float* lrow = latent + (size_t)n * DO + quad * 8;
#pragma unroll
            for (int e = 0; e < 8; ++e) {
                af2[0][e] = (_Float16)orow[e];
                af2[1][e] = (_Float16)lrow[e];
            }
        }
#pragma unroll
        for (int cti = 0; cti < 2; ++cti) {
            int ct = wave * 2 + cti;
            float bb = hb1[ct * 16 + l15];
            floatx4 acc = {bb, bb, bb, bb};
#pragma unroll
            for (int ks = 0; ks < 2; ++ks) {
                const float* wsrc = hw1 + (size_t)(ks * 32 + quad * 8) * HID + ct * 16 + l15;
                half8 bf;
#pragma unroll
                for (int e = 0; e < 8; ++e) bf[e] = (_Float16)wsrc[(size_t)e * HID];
                acc = __builtin_amdgcn_mfma_f32_16x16x32_f16(af2[ks], bf, acc, 0, 0, 0);
            }
#pragma unroll
            for (int reg = 0; reg < 4; ++reg)
                hf[(size_t)(n0 + quad * 4 + reg) * HID + ct * 16 + l15] =
                    (_Float16)fmaxf(acc[reg], 0.f);
        }
    }
}

// ---------------------------------------------------------------------------
// Kernel GEMM: 512 blocks x 256 threads (4 waves). PURE hyper-GEMM:
//  block = 128 rows x 16 emb-cols x all 64 d.
//  - full-M: every wave holds A-frags for ALL 128 rows (32 half8 = 128 VGPR)
//    -> each B-fragment ds_read feeds 8 MFMAs.
//  - wave-private 16-d set; depth-3 double... triple-buffered B staging via
//    global_load_lds; counted `s_waitcnt vmcnt(8)` (static literals, loop
//    fully unrolled); NO __syncthreads in the loop.
//  - bias in 16 static VGPRs; xs_t [64][128] f32 XOR-swizzled (staging
//    writes 2-way instead of 16-way).
//  LDS = 32768 (xs) + 49152 (Bs[4][3][2048]) = 81920 B -> 2 blocks/CU.
//  - epilogue: cross-wave d-reduction (reuses xs region), tanh, embf +
//    per-batch mean.
// ---------------------------------------------------------------------------
__global__ __launch_bounds__(256, 2)
void k_gemm(const float* __restrict__ obs, const float* __restrict__ latent,
            const _Float16* __restrict__ hf, const _Float16* __restrict__ w2p,
            const float* __restrict__ hb2,
            _Float16* __restrict__ embf, _Float16* __restrict__ emeanf) {
    __shared__ __align__(16) char smraw[81920];
    float (*xs_t)[128] = (float(*)[128])smraw;                       // 32 KB
    _Float16 (*Bs)[3][2048] = (_Float16(*)[3][2048])(smraw + 32768); // 48 KB

    int b   = blockIdx.x;
    int tid = threadIdx.x;
    int wave = tid >> 6, lane = tid & 63, l15 = lane & 15, quad = lane >> 4;

    int jt = b & 7;          // emb col-tile (16 cols) — XCD-aligned B reuse
    int rt = b >> 3;         // row-tile: rows [rt*128, +128)
    int n0 = rt * 128;
    int j0 = jt * 16;

    // stage x TRANSPOSED + swizzled: element (d=c, row=r) -> xs_t[c][r^XSW(c)]
    for (int i = tid; i < 128 * 16; i += 256) {
        int r = i >> 4, c4 = (i & 15) * 4;
        float4 v;
        if (c4 < DS) v = *(const float4*)(obs + ((n0 + r) & (BATCH - 1)) * DS + c4);
        else         v = *(const float4*)(latent + (size_t)(n0 + r) * DO + (c4 - DS));
        xs_t[c4 + 0][r ^ XSW(c4 + 0)] = v.x;
        xs_t[c4 + 1][r ^ XSW(c4 + 1)] = v.y;
        xs_t[c4 + 2][r ^ XSW(c4 + 2)] = v.z;
        xs_t[c4 + 3][r ^ XSW(c4 + 3)] = v.w;
    }

    // full-M A-frags from hf (global, L2): 32 x half8 = 128 VGPR
    half8 af[8][4];
#pragma unroll
    for (int t = 0; t < 8; ++t)
#pragma unroll
        for (int ks = 0; ks < 4; ++ks)
            af[t][ks] = *(const half8*)(hf + (size_t)(n0 + t * 16 + l15) * HID
                                           + ks * 32 + quad * 8);

    // bias: 16 statically-indexed VGPRs (d(i) = (i>>1)*8 + wave*2 + (i&1))
    float bias_r[16];
#pragma unroll
    for (int i = 0; i < 16; ++i) {
        int d = (i >> 1) * 8 + wave * 2 + (i & 1);
        bias_r[i] = hb2[d * HID + j0 + l15];
    }

    // prologue: stage buffers 0..2 (d(0), d(1), d(2))
    const _Float16* wbase = w2p + (size_t)jt * 2048 + lane * 8;
#pragma unroll
    for (int p = 0; p < 3; ++p) {
        int d = (p >> 1) * 8 + wave * 2 + (p & 1);
        const _Float16* src = wbase + (size_t)d * 16384;
        _Float16* dst = &Bs[wave][p][0];
#pragma unroll
        for (int kt = 0; kt < 4; ++kt)
            async_ld16(dst + kt * 512, src + kt * 512);
    }
    __syncthreads();   // xs_t visible to all waves (also drains prologue)

    float emb_acc[8][4];
#pragma unroll
    for (int t = 0; t < 8; ++t)
#pragma unroll
        for (int reg = 0; reg < 4; ++reg) emb_acc[t][reg] = 0.f;

    // ---- main loop: fully unrolled, no barriers, counted vmcnt ----
#pragma unroll
    for (int i = 0; i < 16; ++i) {
        if (i <= 13)      asm volatile("s_waitcnt vmcnt(8)" ::: "memory");
        else if (i == 14) asm volatile("s_waitcnt vmcnt(4)" ::: "memory");
        else              asm volatile("s_waitcnt vmcnt(0)" ::: "memory");
        __builtin_amdgcn_sched_barrier(0);

        int d = (i >> 1) * 8 + wave * 2 + (i & 1);
        int buf = i % 3;
        half8 bfr0 = *(const half8*)&Bs[wave][buf][0 * 512 + lane * 8];
        half8 bfr1 = *(const half8*)&Bs[wave][buf][1 * 512 + lane * 8];
        half8 bfr2 = *(const half8*)&Bs[wave][buf][2 * 512 + lane * 8];
        half8 bfr3 = *(const half8*)&Bs[wave][buf][3 * 512 + lane * 8];
        float bb = bias_r[i];
        int rsw = XSW(d);

        __builtin_amdgcn_s_setprio(1);
#pragma unroll
        for (int t = 0; t < 8; ++t) {
            floatx4 acc = {bb, bb, bb, bb};
            acc = __builtin_amdgcn_mfma_f32_16x16x32_f16(af[t][0], bfr0, acc, 0, 0, 0);
            acc = __builtin_amdgcn_mfma_f32_16x16x32_f16(af[t][1], bfr1, acc, 0, 0, 0);
            acc = __builtin_amdgcn_mfma_f32_16x16x32_f16(af[t][2], bfr2, acc, 0, 0, 0);
            acc = __builtin_amdgcn_mfma_f32_16x16x32_f16(af[t][3], bfr3, acc, 0, 0, 0);
            floatx4 xv = *(const floatx4*)&xs_t[d][(t * 16 + quad * 4) ^ rsw];
#pragma unroll
            for (int reg = 0; reg < 4; ++reg)
                emb_acc[t][reg] = fmaf(xv[reg], fmaxf(acc[reg], 0.f), emb_acc[t][reg]);
        }
        __builtin_amdgcn_s_setprio(0);

        if (i + 3 < 16) {   // restage the just-consumed buffer for step i+3
            int dn = ((i + 3) >> 1) * 8 + wave * 2 + ((i + 3) & 1);
            const _Float16* src = wbase + (size_t)dn * 16384;
            _Float16* dst = &Bs[wave][buf][0];
#pragma unroll
            for (int kt = 0; kt < 4; ++kt)
                async_ld16(dst + kt * 512, src + kt * 512);
        }
    }
    __syncthreads();   // all waves done with xs_t; safe to reuse as red[]

    // ---- cross-wave d-reduction + tanh + mean ----
    float* red = (float*)smraw;   // [4][128][16] f32 = 32 KB (xs region)
#pragma unroll
    for (int t = 0; t < 8; ++t)
#pragma unroll
        for (int reg = 0; reg < 4; ++reg)
            red[((wave * 128) + t * 16 + quad * 4 + reg) * 16 + l15] = emb_acc[t][reg];
    __syncthreads();
#pragma unroll
    for (int t2 = 0; t2 < 2; ++t2) {
        float e[4];
#pragma unroll
        for (int rr = 0; rr < 4; ++rr) {
            int row = wave * 32 + t2 * 16 + quad * 4 + rr;
            float s = red[(0 * 128 + row) * 16 + l15] + red[(1 * 128 + row) * 16 + l15]
                    + red[(2 * 128 + row) * 16 + l15] + red[(3 * 128 + row) * 16 + l15];
            e[rr] = tanhf(s);
            embf[(size_t)(n0 + row) * HID + j0 + l15] = (_Float16)e[rr];
        }
        float m = e[0] + e[1] + e[2] + e[3];
        m += __shfl_xor(m, 16, 64);
        m += __shfl_xor(m, 32, 64);
        if (quad == 0)
            emeanf[(size_t)(rt * 8 + wave * 2 + t2) * HID + j0 + l15] =
                (_Float16)(m * (1.f / 16));
    }
}

// ---------------------------------------------------------------------------
// Kernel T (fused tail), 512 blocks x 16 rows (1 softmax group each).
// ---------------------------------------------------------------------------
__global__ __launch_bounds__(512, 4)
void k_tail(const _Float16* __restrict__ embf, const _Float16* __restrict__ emeanf,
            const _Float16* __restrict__ vw1p, const float* __restrict__ vb1,
            const _Float16* __restrict__ vw2p, const float* __restrict__ vb2,
            const _Float16* __restrict__ aw1p, const float* __restrict__ ab1,
            const _Float16* __restrict__ aw2p, const float* __restrict__ ab2,
            const float* __restrict__ aw3, const float* __restrict__ ab3,
            float* __restrict__ out) {
    __shared__ _Float16 embs[16][LSTR];
    __shared__ _Float16 means[16][LSTR];
    __shared__ _Float16 tAs[16][LSTR];
    __shared__ _Float16 tBs[16][LSTR];
    __shared__ float scr[16][32];
    __shared__ float satt[16];
    __shared__ float att[16];
    int g = blockIdx.x;       // batch 0..511
    int n0 = g * 16;
    int tid = threadIdx.x;
    int wave = tid >> 6, lane = tid & 63, l15 = lane & 15, quad = lane >> 4;
    int ct = wave;            // wave owns col-tile ct of 8

    {   // stage emb rows + mean rows (512 half8 loads = 1/thread)
        int m = tid >> 8, r = (tid >> 4) & 15, c8 = (tid & 15) * 8;
        if (m == 0)
            *(half8*)&embs[r][c8] = *(const half8*)(embf + (size_t)(n0 + r) * HID + c8);
        else
            *(half8*)&means[r][c8] =
                *(const half8*)(emeanf + (size_t)((n0 & 511) + r) * HID + c8);
    }
    __syncthreads();

    half8 av[4], amean[4];
#pragma unroll
    for (int ks = 0; ks < 4; ++ks) {
        av[ks]    = *(const half8*)&embs[l15][ks * 32 + quad * 8];
        amean[ks] = *(const half8*)&means[l15][ks * 32 + quad * 8];
    }

    // ---- v1: t1 = relu(emb @ vw1 + vb1) ----
    floatx4 acc;
    {
        float bb = vb1[ct * 16 + l15];
        acc = (floatx4){bb, bb, bb, bb};
    }
#pragma unroll
    for (int ks = 0; ks < 4; ++ks) {
        half8 bfr = *(const half8*)(vw1p + ((size_t)ct * 4 + ks) * 512 + lane * 8);
        acc = __builtin_amdgcn_mfma_f32_16x16x32_f16(av[ks], bfr, acc, 0, 0, 0);
    }
#pragma unroll
    for (int reg = 0; reg < 4; ++reg)
        tAs[quad * 4 + reg][ct * 16 + l15] = (_Float16)fmaxf(acc[reg], 0.f);
    __syncthreads();

    half8 at[4];
#pragma unroll
    for (int ks = 0; ks < 4; ++ks)
        at[ks] = *(const half8*)&tAs[l15][ks * 32 + quad * 8];

    // ---- v2: vals = relu(t1 @ vw2 + vb2), kept in registers ----
    floatx4 vacc;
    {
        float bb = vb2[ct * 16 + l15];
        vacc = (floatx4){bb, bb, bb, bb};
    }
#pragma unroll
    for (int ks = 0; ks < 4; ++ks) {
        half8 bfr = *(const half8*)(vw2p + ((size_t)ct * 4 + ks) * 512 + lane * 8);
        vacc = __builtin_amdgcn_mfma_f32_16x16x32_f16(at[ks], bfr, vacc, 0, 0, 0);
    }

    // ---- a1: ta1 = relu([emb|mean] @ aw1 + ab1), K=256 ----
    floatx4 aacc;
    {
        float bb = ab1[ct * 16 + l15];
        aacc = (floatx4){bb, bb, bb, bb};
    }
#pragma unroll
    for (int ks = 0; ks < 8; ++ks) {
        half8 bfr = *(const half8*)(aw1p + ((size_t)ct * 8 + ks) * 512 + lane * 8);
        half8 a = (ks < 4) ? av[ks] : amean[ks - 4];
        aacc = __builtin_amdgcn_mfma_f32_16x16x32_f16(a, bfr, aacc, 0, 0, 0);
    }
#pragma unroll
    for (int reg = 0; reg < 4; ++reg)
        tBs[quad * 4 + reg][ct * 16 + l15] = (_Float16)fmaxf(aacc[reg], 0.f);
    __syncthreads();

    half8 aa[4];
#pragma unroll
    for (int ks = 0; ks < 4; ++ks)
        aa[ks] = *(const half8*)&tBs[l15][ks * 32 + quad * 8];

    // ---- a2: t2 = relu(ta1 @ aw2 + ab2) -> tAs ----
    floatx4 a2acc;
    {
        float bb = ab2[ct * 16 + l15];
        a2acc = (floatx4){bb, bb, bb, bb};
    }
#pragma unroll
    for (int ks = 0; ks < 4; ++ks) {
        half8 bfr = *(const half8*)(aw2p + ((size_t)ct * 4 + ks) * 512 + lane * 8);
        a2acc = __builtin_amdgcn_mfma_f32_16x16x32_f16(aa[ks], bfr, a2acc, 0, 0, 0);
    }
    __syncthreads();   // everyone done reading tAs (at) from v1 stage
#pragma unroll
    for (int reg = 0; reg < 4; ++reg)
        tAs[quad * 4 + reg][ct * 16 + l15] = (_Float16)fmaxf(a2acc[reg], 0.f);
    __syncthreads();

    // ---- scores: s[r] = t2[r,:] . aw3 + ab3 ----
    {
        int r = tid >> 5, ch = tid & 31;
        float p = 0.f;
#pragma unroll
        for (int k = 0; k < 4; ++k)
            p += (float)tAs[r][ch * 4 + k] * aw3[ch * 4 + k];
        scr[r][ch] = p;
    }
    __syncthreads();
    if (tid < 16) {
        float s = ab3[0];
#pragma unroll
        for (int ch = 0; ch < 32; ++ch) s += scr[tid][ch];
        satt[tid] = s;
    }
    __syncthreads();
    if (tid < 16) {
        float m = -1e30f;
#pragma unroll
        for (int a = 0; a < 16; ++a) m = fmaxf(m, satt[a]);
        float S = 0.f;
#pragma unroll
        for (int a = 0; a < 16; ++a) S += expf(satt[a] - m);
        att[tid] = expf(satt[tid] - m) / S;
    }
    __syncthreads();

    // ---- weighted sum: out[g, col] = sum_a att[a] * vals[a, col] ----
    {
        float p = 0.f;
#pragma unroll
        for (int reg = 0; reg < 4; ++reg)
            p += att[quad * 4 + reg] * fmaxf(vacc[reg], 0.f);
        p += __shfl_xor(p, 16, 64);
        p += __shfl_xor(p, 32, 64);
        if (quad == 0) out[(size_t)g * HID + ct * 16 + l15] = p;
    }
}

// ---------------------------------------------------------------------------
extern "C" void kernel_launch(void* const* d_in, const int* in_sizes, int n_in,
                              void* d_out, int out_size, void* d_ws, size_t ws_size,
                              hipStream_t stream) {
    const float* obs = (const float*)d_in[0];
    const float* lat = (const float*)d_in[1];
    const float* hw1 = (const float*)d_in[2];
    const float* hb1 = (const float*)d_in[3];
    const float* hw2 = (const float*)d_in[4];
    const float* hb2 = (const float*)d_in[5];
    const float* vw1 = (const float*)d_in[6];
    const float* vb1 = (const float*)d_in[7];
    const float* vw2 = (const float*)d_in[8];
    const float* vb2 = (const float*)d_in[9];
    const float* aw1 = (const float*)d_in[10];
    const float* ab1 = (const float*)d_in[11];
    const float* aw2 = (const float*)d_in[12];
    const float* ab2 = (const float*)d_in[13];
    const float* aw3 = (const float*)d_in[14];
    const float* ab3 = (const float*)d_in[15];
    float* out = (float*)d_out;

    char* ws = (char*)d_ws;
    _Float16*  hf     = (_Float16*)ws;  ws += (size_t)NROWS * HID * 2;     // 2 MB
    _Float16*  w2p    = (_Float16*)ws;  ws += (size_t)WCOLS * HID * 2;     // 2 MB
    _Float16*  embf   = (_Float16*)ws;  ws += (size_t)NROWS * HID * 2;     // 2 MB
    _Float16*  emeanf = (_Float16*)ws;  ws += (size_t)BATCH * HID * 2;     // 128 KB
    _Float16*  vw1p   = (_Float16*)ws;  ws += (size_t)HID * HID * 2;       // 32 KB
    _Float16*  vw2p   = (_Float16*)ws;  ws += (size_t)HID * HID * 2;
    _Float16*  aw1p   = (_Float16*)ws;  ws += (size_t)2 * HID * HID * 2;   // 64 KB
    _Float16*  aw2p   = (_Float16*)ws;  ws += (size_t)HID * HID * 2;

    hipLaunchKernelGGL(k_prep, dim3(PACK_BLOCKS + NROWS / 16), dim3(256), 0, stream,
                       obs, lat, hw1, hb1, hw2, vw1, vw2, aw1, aw2,
                       hf, w2p, vw1p, vw2p, aw1p, aw2p);
    hipLaunchKernelGGL(k_gemm, dim3(512), dim3(256), 0, stream,
                       obs, lat, hf, w2p, hb2, embf, emeanf);
    hipLaunchKernelGGL(k_tail, dim3(BATCH), dim3(512), 0, stream,
                       embf, emeanf, vw1p, vb1, vw2p, vb2,
                       aw1p, ab1, aw2p, ab2, aw3, ab3, out);
}